// Round 10
// baseline (209.009 us; speedup 1.0000x reference)
//
#include <hip/hip_runtime.h>

// ============================================================================
// ROUND 22: attn_split restructured — KVBLK=64, NBUF=3 (48KB), ONE barrier
// per phase ([wait(2) -> sbar -> stage(c+2) -> compute(c)], the race-free
// qkv-R15 rotation), 2-phase staging cover, setprio(1) around MFMA clusters.
// R21 counters (VALU 31 / MFMA 11 / HBM 6 / Occ 40, conflicts 0) showed
// phase-locked pipe ping-pong: 2 barriers/phase forced all 16 waves through
// softmax (VALU wall) and MFMA in lockstep. Halved phase quantum + wave
// drift + priority lets softmax of one wave overlap MFMA of another.
// Same verified fragment formulas (t,ks2 ranges halved); V 32-col-group
// permutation and m-accumulation order preserved -> bit-identical output.
// prep/combine (R21 output-linear), qkv_gemm (R15 best), o_gemm unchanged.
// ============================================================================

typedef __attribute__((ext_vector_type(8))) short short8;
typedef __attribute__((ext_vector_type(4))) short short4v;
typedef __attribute__((ext_vector_type(4))) float f32x4;
typedef __attribute__((ext_vector_type(4))) int int4v;
typedef __attribute__((ext_vector_type(2))) int int2v;

#define SCL2E 0.18033688011112042592f /* (1/8) * log2(e) */

__device__ __forceinline__ float bf2f(short s) {
  unsigned u = ((unsigned)(unsigned short)s) << 16;
  return __uint_as_float(u);
}
__device__ __forceinline__ short f2bf(float f) {
  unsigned u = __float_as_uint(f);
  u += 0x7fffu + ((u >> 16) & 1u);
  return (short)(u >> 16);
}
__device__ __forceinline__ int cvt_pk_bf16(float a, float b) {
  int r;
  asm("v_cvt_pk_bf16_f32 %0, %1, %2" : "=v"(r) : "v"(a), "v"(b));
  return r;
}
__device__ __forceinline__ void gld_lds16(const void* gp, void* lp) {
  __builtin_amdgcn_global_load_lds(
      (const __attribute__((address_space(1))) unsigned int*)gp,
      (__attribute__((address_space(3))) unsigned int*)lp, 16, 0, 0);
}
// Barrier with scheduling fences (no implicit waitcnt).
__device__ __forceinline__ void sbar() {
  __builtin_amdgcn_sched_barrier(0);
  __builtin_amdgcn_s_barrier();
  __builtin_amdgcn_sched_barrier(0);
}
#define WAITVM(N) asm volatile("s_waitcnt vmcnt(" #N ")" ::: "memory")

__device__ __forceinline__ void pipesync() {
  asm volatile("s_waitcnt vmcnt(0) lgkmcnt(0)" ::: "memory");
  __builtin_amdgcn_sched_barrier(0);
  __builtin_amdgcn_s_barrier();
  __builtin_amdgcn_sched_barrier(0);
}
__device__ __forceinline__ short4v cvt4(float4 v) {
  short4v o;
  o[0] = f2bf(v.x); o[1] = f2bf(v.y); o[2] = f2bf(v.z); o[3] = f2bf(v.w);
  return o;
}

// ---------------------------------------------------------------------------
// prep (R21): mask bit-pack + fp32->bf16 tiled conversion, OUTPUT-LINEAR.
// ---------------------------------------------------------------------------
__global__ __launch_bounds__(256) void prep(
    const unsigned char* __restrict__ mask, unsigned long long* __restrict__ pm,
    const float* __restrict__ Wq, const float* __restrict__ Wkv,
    const float* __restrict__ Wo, const float* __restrict__ x,
    const float* __restrict__ ctx, short* __restrict__ wqb,
    short* __restrict__ wkvb, short* __restrict__ wob,
    short* __restrict__ xb, short* __restrict__ ctxb) {
  const int row = blockIdx.x;
  const int wave = threadIdx.x >> 6, lane = threadIdx.x & 63;
  const unsigned char p8 = mask[lane * 4 + 1];
  const int p32 = ((const int*)mask)[lane * 2 + 1];
  const int shift =
      (__ballot(p8 != 0) != 0ull) ? 0 : ((__ballot(p32 != 0) != 0ull) ? 2 : 3);
  const size_t mbase = ((size_t)row * 2048) << shift;
#pragma unroll
  for (int j = 0; j < 8; j++) {
    const int c = wave * 512 + j * 64 + lane;
    const unsigned long long bits = __ballot(mask[mbase + ((size_t)c << shift)] != 0);
    if (lane == 0) pm[(size_t)row * 32 + wave * 8 + j] = bits;
  }
  const int gid = blockIdx.x * 256 + threadIdx.x;  // [0, 524288)
  {  // xb: 2048x1024, 128-tiled
    const int T = gid * 4;
    const int j = T & 4, r15 = (T >> 3) & 15, q = (T >> 7) & 3;
    const int f = (T >> 9) & 7, kc = (T >> 12) & 31, rt = T >> 17;
    const int r = rt * 128 + f * 16 + r15, k = kc * 32 + q * 8 + j;
    *(short4v*)(xb + T) = cvt4(*(const float4*)(x + (((size_t)r) << 10) + k));
  }
#pragma unroll
  for (int it = 0; it < 2; it++) {  // ctxb: 4096x1024, 128-tiled
    const int T = (gid + it * 524288) * 4;
    const int j = T & 4, r15 = (T >> 3) & 15, q = (T >> 7) & 3;
    const int f = (T >> 9) & 7, kc = (T >> 12) & 31, rt = T >> 17;
    const int r = rt * 128 + f * 16 + r15, k = kc * 32 + q * 8 + j;
    *(short4v*)(ctxb + T) = cvt4(*(const float4*)(ctx + (((size_t)r) << 10) + k));
  }
  {  // wkvb: 2048x1024, 128-tiled
    const int T = gid * 4;
    const int j = T & 4, r15 = (T >> 3) & 15, q = (T >> 7) & 3;
    const int f = (T >> 9) & 7, kc = (T >> 12) & 31, rt = T >> 17;
    const int r = rt * 128 + f * 16 + r15, k = kc * 32 + q * 8 + j;
    *(short4v*)(wkvb + T) = cvt4(*(const float4*)(Wkv + (((size_t)r) << 10) + k));
  }
  if (gid < 262144) {  // Wq 128-tiled; Wo 64-tiled
    const int T = gid * 4;
    {
      const int j = T & 4, r15 = (T >> 3) & 15, q = (T >> 7) & 3;
      const int f = (T >> 9) & 7, kc = (T >> 12) & 31, rt = T >> 17;
      const int r = rt * 128 + f * 16 + r15, k = kc * 32 + q * 8 + j;
      *(short4v*)(wqb + T) = cvt4(*(const float4*)(Wq + (((size_t)r) << 10) + k));
    }
    {
      const int j = T & 4, r15 = (T >> 3) & 15, q = (T >> 7) & 3;
      const int f = (T >> 9) & 3, kc = (T >> 11) & 31, rt = T >> 16;
      const int r = rt * 64 + f * 16 + r15, k = kc * 32 + q * 8 + j;
      *(short4v*)(wob + T) = cvt4(*(const float4*)(Wo + (((size_t)r) << 10) + k));
    }
  }
}

// ---------------------------------------------------------------------------
// qkv_gemm (R15 exact, measured best): 128x128 tile, BK=32, NBUF=3 (48KB),
// counted vmcnt(4), one barrier per phase, XCD-chunked swizzle, 3 blocks/CU.
// ---------------------------------------------------------------------------
__global__ __launch_bounds__(256, 3)
void qkv_gemm(const short* __restrict__ xb, const short* __restrict__ ctxb,
              const short* __restrict__ wqb, const short* __restrict__ wkvb,
              const float* __restrict__ bias, short* __restrict__ qws,
              short* __restrict__ kws, short* __restrict__ vtws) {
  __shared__ __align__(16) short ldsA[3][4096];
  __shared__ __align__(16) short ldsB[3][4096];
  const int tid = threadIdx.x;
  const int wave = tid >> 6, lane = tid & 63;
  const int l15 = lane & 15, lg = lane >> 4;
  const int bx0 = blockIdx.x;
  const int bx = (bx0 & 7) * 80 + (bx0 >> 3);
  const bool isKV = bx < 512;
  const int rt = isKV ? (bx >> 4) : ((bx - 512) >> 3);
  const int ct = isKV ? (bx & 15) : ((bx - 512) & 7);
  const short* Amat = isKV ? ctxb : xb;
  const short* Bw = isKV ? wkvb : wqb;
  const int wr = wave >> 1, wc = wave & 1;

  f32x4 acc[4][4];
#pragma unroll
  for (int i = 0; i < 4; i++)
#pragma unroll
    for (int j = 0; j < 4; j++) acc[i][j] = (f32x4){0.f, 0.f, 0.f, 0.f};

  const short* ga0 = Amat + (size_t)rt * 131072 + wave * 512 + lane * 8;
  const short* ga1 = ga0 + 2048;
  const short* gb0 = Bw + (size_t)ct * 131072 + wave * 512 + lane * 8;
  const short* gb1 = gb0 + 2048;

  auto stage = [&](int kk, int buf) {
    const size_t koff = (size_t)kk * 4096;
    short* dA = &ldsA[buf][0];
    short* dB = &ldsB[buf][0];
    gld_lds16(ga0 + koff, dA + wave * 512);
    gld_lds16(ga1 + koff, dA + (wave + 4) * 512);
    gld_lds16(gb0 + koff, dB + wave * 512);
    gld_lds16(gb1 + koff, dB + (wave + 4) * 512);
  };
  auto compute = [&](int buf) {
    const short* sA = &ldsA[buf][0];
    const short* sB = &ldsB[buf][0];
    short8 af[4], bfr[4];
#pragma unroll
    for (int t = 0; t < 4; t++)
      af[t] = *(const short8*)&sA[((wr * 4 + t) * 64 + lane) * 8];
#pragma unroll
    for (int t = 0; t < 4; t++)
      bfr[t] = *(const short8*)&sB[((wc * 4 + t) * 64 + lane) * 8];
#pragma unroll
    for (int i = 0; i < 4; i++)
#pragma unroll
      for (int j = 0; j < 4; j++)
        acc[i][j] =
            __builtin_amdgcn_mfma_f32_16x16x32_bf16(af[i], bfr[j], acc[i][j], 0, 0, 0);
  };

  stage(0, 0);
  stage(1, 1);
  int cur = 0, nxt = 2;
  for (int i = 0; i < 30; ++i) {
    WAITVM(4);
    sbar();
    stage(i + 2, nxt);
    compute(cur);
    cur = (cur == 2) ? 0 : cur + 1;
    nxt = (nxt == 2) ? 0 : nxt + 1;
  }
  WAITVM(4);
  sbar();
  compute(cur);
  cur = (cur == 2) ? 0 : cur + 1;
  WAITVM(0);
  sbar();
  compute(cur);

#pragma unroll
  for (int i = 0; i < 4; i++)
#pragma unroll
    for (int j = 0; j < 4; j++)
#pragma unroll
      for (int r = 0; r < 4; r++) {
        const int gr = rt * 128 + wr * 64 + i * 16 + lg * 4 + r;
        const int gc = ct * 128 + wc * 64 + j * 16 + l15;
        float v = acc[i][j][r];
        if (isKV) {
          v += bias[gc];
          const int b = gr >> 11, m = gr & 2047;
          const int kv = gc >> 10, hh = (gc >> 6) & 15, d = gc & 63;
          if (kv == 0)
            kws[((((size_t)b * 16 + hh) * 2048 + m) << 6) + d] = f2bf(v);
          else {
            // permuted V^T column so attn's in-register P-frag order matches
            const int mp = (m & ~31) | (((m >> 2) & 3) << 3) |
                           (((m >> 4) & 1) << 2) | (m & 3);
            vtws[(((size_t)b * 16 + hh) * 64 + d) * 2048 + mp] = f2bf(v);
          }
        } else {
          const int b = gr >> 10, n = gr & 1023, hh = gc >> 6, d = gc & 63;
          qws[((((size_t)b * 16 + hh) * 1024 + n) << 6) + d] = f2bf(v * SCL2E);
        }
      }
}

// ---------------------------------------------------------------------------
// attn_split (R22): KVBLK=64, NBUF=3 (48KB), one barrier per phase
// [wait(2) -> sbar -> stage(c+2) -> compute(c)], setprio around MFMA.
// 512 blocks x 512 threads, split-K x2. Swapped QK^T in-register P.
// ---------------------------------------------------------------------------
__global__ __launch_bounds__(512, 4)
void attn_split(const short* __restrict__ Qg, const short* __restrict__ Kg,
                const short* __restrict__ Vtg,
                const unsigned int* __restrict__ pm,
                float* __restrict__ opart, float* __restrict__ lpart) {
  __shared__ __align__(16) short ldsK[3][4096];
  __shared__ __align__(16) short ldsV[3][4096];
  const int tid = threadIdx.x;
  const int w = tid >> 6, lane = tid & 63;
  const int l15 = lane & 15, lg = lane >> 4;
  const int bx = blockIdx.x;
  const int bhid = bx & 31, qt = (bx >> 5) & 7, half = bx >> 8;
  const int b = bhid >> 4, h = bhid & 15;
  const int n0 = qt * 128, m_base = half * 1024;
  const size_t bh = (size_t)b * 16 + h;
  const short* Qb = Qg + (bh * 1024 + n0) * 64;
  const short* Kb = Kg + (bh << 17);
  const short* Vb = Vtg + (bh << 17);
  // mask words for row n (broadcast across lg); 2 words per 64-col phase
  const unsigned int* pmw =
      pm + ((size_t)(b * 1024 + n0 + w * 16 + l15) << 6) + (m_base >> 5);

  // Preload all 32 mask words (16 phases x 2) as 8 uint4 (32 VGPR).
  uint4 mku[8];
#pragma unroll
  for (int i = 0; i < 8; i++) mku[i] = *(const uint4*)(pmw + i * 4);

  // stage tile c (64 m-cols): 8 K frag-sets + 8 V frag-sets; wave w does f=w.
  auto stageKV = [&](int c, int buf) {
    const int m0 = m_base + c * 64;
    const int t = w >> 1, ks = w & 1;       // K: rows m0+t*16+l15, d-half ks
    gld_lds16(Kb + (size_t)(m0 + t * 16 + l15) * 64 + ks * 32 + lg * 8,
              &ldsK[buf][w * 512]);
    const int vt = w >> 1, vk = w & 1;      // V: d-block vt, m-half vk
    gld_lds16(Vb + (size_t)(vt * 16 + l15) * 2048 + (m0 + vk * 32 + lg * 8),
              &ldsV[buf][w * 512]);
  };

  // Prologue: Q (16 frag-sets, 16KB) -> K-parts of buf1,buf2; tile 0 -> buf0.
#pragma unroll
  for (int ii = 0; ii < 2; ii++) {
    const int f = w * 2 + ii;
    const int t = f >> 1, ks = f & 1;
    short* dst = (f < 8) ? &ldsK[1][f * 512] : &ldsK[2][(f - 8) * 512];
    gld_lds16(Qb + (size_t)(t * 16 + l15) * 64 + ks * 32 + lg * 8, dst);
  }
  stageKV(0, 0);
  pipesync();
  short8 qf[2];
#pragma unroll
  for (int ks = 0; ks < 2; ks++) {
    const int f = w * 2 + ks;
    const short* src = (f < 8) ? &ldsK[1][f * 512] : &ldsK[2][(f - 8) * 512];
    qf[ks] = *(const short8*)&src[lane * 8];
  }
  asm volatile("s_waitcnt lgkmcnt(0)" ::: "memory");
  sbar();
  stageKV(1, 1);  // tile 1 in flight across phase 0

  short8 onesf;
#pragma unroll
  for (int i = 0; i < 8; i++) onesf[i] = (short)0x3F80;  // bf16 1.0

  f32x4 o[4], lacc;
#pragma unroll
  for (int ct = 0; ct < 4; ct++) o[ct] = (f32x4){0.f, 0.f, 0.f, 0.f};
  lacc = (f32x4){0.f, 0.f, 0.f, 0.f};
  const int sb = lg * 4;

  // compute tile c from buf: 8 QK MFMA, 16 exp2, 8 cvt_pk, 8 PV + 2 lacc MFMA
  auto computeC = [&](unsigned int mw0, unsigned int mw1, int buf) {
    const short* sK = &ldsK[buf][0];
    const short* sV = &ldsV[buf][0];
    f32x4 s[4];
#pragma unroll
    for (int t = 0; t < 4; t++) s[t] = (f32x4){0.f, 0.f, 0.f, 0.f};
    __builtin_amdgcn_s_setprio(1);
#pragma unroll
    for (int t = 0; t < 4; t++)
#pragma unroll
      for (int ks = 0; ks < 2; ks++) {
        const short8 kf = *(const short8*)&sK[((t * 2 + ks) * 64 + lane) * 8];
        s[t] = __builtin_amdgcn_mfma_f32_16x16x32_bf16(kf, qf[ks], s[t], 0, 0, 0);
      }
    __builtin_amdgcn_s_setprio(0);
    int2v pw[2];
#pragma unroll
    for (int t = 0; t < 4; t++) {
      const unsigned int mw = (t >> 1) ? mw1 : mw0;
      float p[4];
#pragma unroll
      for (int r = 0; r < 4; r++) {
        const bool att = (mw >> (((t & 1) << 4) + sb + r)) & 1;
        p[r] = exp2f(att ? s[t][r] : -1e30f);
      }
      pw[t >> 1][(t & 1) * 2] = cvt_pk_bf16(p[0], p[1]);
      pw[t >> 1][(t & 1) * 2 + 1] = cvt_pk_bf16(p[2], p[3]);
    }
    // pw[ks2] is only half a frag (4 bf16-pairs = 2 regs)?? No: pw[ks2] is
    // int2v = 2 words = 4 bf16 -> P covers K=32 via 8 bf16. Assemble short8
    // from pw[ks2] words 0..1 plus... (see note) -- P frag for slice ks2
    // needs 4 words: t in {2*ks2, 2*ks2+1} give words 0..3 of the slice.
    __builtin_amdgcn_s_setprio(1);
#pragma unroll
    for (int ks2 = 0; ks2 < 2; ks2++) {
      int4v pwf;
      pwf[0] = pw[ks2][0]; pwf[1] = pw[ks2][1];
      pwf[2] = pw[ks2][2]; pwf[3] = pw[ks2][3];
      const short8 pf = __builtin_bit_cast(short8, pwf);
#pragma unroll
      for (int ct = 0; ct < 4; ct++) {
        const short8 vf = *(const short8*)&sV[((ct * 2 + ks2) * 64 + lane) * 8];
        o[ct] = __builtin_amdgcn_mfma_f32_16x16x32_bf16(pf, vf, o[ct], 0, 0, 0);
      }
      lacc = __builtin_amdgcn_mfma_f32_16x16x32_bf16(pf, onesf, lacc, 0, 0, 0);
    }
    __builtin_amdgcn_s_setprio(0);
  };
  (void)computeC;

  // NOTE on pw sizing: slice ks2 covers m-local t in {2ks2, 2ks2+1} -> 4
  // words. Use int4v pw4[2] directly (t>>1 indexes slice, (t&1)*2+w word).
  auto computeC4 = [&](unsigned int mw0, unsigned int mw1, int buf) {
    const short* sK = &ldsK[buf][0];
    const short* sV = &ldsV[buf][0];
    f32x4 s[4];
#pragma unroll
    for (int t = 0; t < 4; t++) s[t] = (f32x4){0.f, 0.f, 0.f, 0.f};
    __builtin_amdgcn_s_setprio(1);
#pragma unroll
    for (int t = 0; t < 4; t++)
#pragma unroll
      for (int ks = 0; ks < 2; ks++) {
        const short8 kf = *(const short8*)&sK[((t * 2 + ks) * 64 + lane) * 8];
        s[t] = __builtin_amdgcn_mfma_f32_16x16x32_bf16(kf, qf[ks], s[t], 0, 0, 0);
      }
    __builtin_amdgcn_s_setprio(0);
    int4v pw4[2];
#pragma unroll
    for (int t = 0; t < 4; t++) {
      const unsigned int mw = (t >> 1) ? mw1 : mw0;
      float p[4];
#pragma unroll
      for (int r = 0; r < 4; r++) {
        const bool att = (mw >> (((t & 1) << 4) + sb + r)) & 1;
        p[r] = exp2f(att ? s[t][r] : -1e30f);
      }
      pw4[t >> 1][(t & 1) * 2] = cvt_pk_bf16(p[0], p[1]);
      pw4[t >> 1][(t & 1) * 2 + 1] = cvt_pk_bf16(p[2], p[3]);
    }
    __builtin_amdgcn_s_setprio(1);
#pragma unroll
    for (int ks2 = 0; ks2 < 2; ks2++) {
      const short8 pf = __builtin_bit_cast(short8, pw4[ks2]);
#pragma unroll
      for (int ct = 0; ct < 4; ct++) {
        const short8 vf = *(const short8*)&sV[((ct * 2 + ks2) * 64 + lane) * 8];
        o[ct] = __builtin_amdgcn_mfma_f32_16x16x32_bf16(pf, vf, o[ct], 0, 0, 0);
      }
      lacc = __builtin_amdgcn_mfma_f32_16x16x32_bf16(pf, onesf, lacc, 0, 0, 0);
    }
    __builtin_amdgcn_s_setprio(0);
  };

  // Main loop: 16 phases. [WAITVM(2) -> sbar -> stage(c+2) -> compute(c)].
#pragma unroll
  for (int c = 0; c < 16; c++) {
    if (c < 15) {
      WAITVM(2);
    } else {
      WAITVM(0);
    }
    sbar();
    if (c + 2 < 16) stageKV(c + 2, (c + 2) % 3);
    const uint4 mk = mku[c >> 1];
    const unsigned int mw0 = (c & 1) ? mk.z : mk.x;
    const unsigned int mw1 = (c & 1) ? mk.w : mk.y;
    computeC4(mw0, mw1, c % 3);
  }

#pragma unroll
  for (int ct = 0; ct < 4; ct++)
#pragma unroll
    for (int r = 0; r < 4; r++) {
      const int n = n0 + w * 16 + lg * 4 + r;
      opart[((size_t)half << 21) + (((size_t)b * 1024 + n) << 10) + h * 64 +
            ct * 16 + l15] = o[ct][r];
    }
  if (l15 == 0) {
#pragma unroll
    for (int r = 0; r < 4; r++) {
      const int n = n0 + w * 16 + lg * 4 + r;
      lpart[((size_t)half << 15) + bh * 1024 + n] = lacc[r];
    }
  }
}

// ---------------------------------------------------------------------------
// combine (R21, output-linear): AO = (o0+o1)/(l0+l1), bf16, 64-tiled.
// ---------------------------------------------------------------------------
__global__ __launch_bounds__(256) void combine(
    const float* __restrict__ opart, const float* __restrict__ lpart,
    short* __restrict__ aoT) {
  const int gid = blockIdx.x * 256 + threadIdx.x;  // [0, 524288)
  const int T = gid * 4;
  const int j = T & 4, r15 = (T >> 3) & 15, q = (T >> 7) & 3;
  const int f = (T >> 9) & 3, kc = (T >> 11) & 31, rt = T >> 16;
  const int row = rt * 64 + f * 16 + r15;
  const int col = kc * 32 + q * 8 + j;
  const int b = row >> 10, n = row & 1023, h = col >> 6;
  const size_t src = (((size_t)row) << 10) + col;
  const float4 o1 = *(const float4*)(opart + src);
  const float4 o2 = *(const float4*)(opart + (1u << 21) + src);
  const float l1 = lpart[(size_t)(b * 16 + h) * 1024 + n];
  const float l2 = lpart[(1u << 15) + (size_t)(b * 16 + h) * 1024 + n];
  const float inv = 1.f / fmaxf(l1 + l2, 1e-30f);
  short4v o;
  o[0] = f2bf((o1.x + o2.x) * inv); o[1] = f2bf((o1.y + o2.y) * inv);
  o[2] = f2bf((o1.z + o2.z) * inv); o[3] = f2bf((o1.w + o2.w) * inv);
  *(short4v*)(aoT + T) = o;
}

// ---------------------------------------------------------------------------
// o_gemm (R17, unchanged): 64x64 tiles, BK=64 (16 phases x 8 MFMA),
// 512 blocks, NBUF=3 (48KB LDS, 3 blocks/CU), counted vmcnt(4), XCD swizzle.
// ---------------------------------------------------------------------------
__global__ __launch_bounds__(256, 3)
void o_gemm(const short* __restrict__ aoT, const short* __restrict__ wobT,
            float* __restrict__ Of) {
  __shared__ __align__(16) short ldsA[3][4096];
  __shared__ __align__(16) short ldsB[3][4096];
  const int tid = threadIdx.x;
  const int w = tid >> 6, lane = tid & 63;
  const int l15 = lane & 15, lg = lane >> 4;
  const int bx0 = blockIdx.x;
  const int bx = (bx0 & 7) * 64 + (bx0 >> 3);
  const int rt = bx >> 4, ct = bx & 15;

  f32x4 acc[4];
#pragma unroll
  for (int j = 0; j < 4; j++) acc[j] = (f32x4){0.f, 0.f, 0.f, 0.f};

  const short* ga = aoT + (size_t)rt * 65536 + w * 512 + lane * 8;
  const short* gb = wobT + (size_t)ct * 65536 + w * 512 + lane * 8;

  auto stage = [&](int t, int buf) {
    const size_t koff = (size_t)t * 4096;
    gld_lds16(ga + koff, &ldsA[buf][0] + w * 512);
    gld_lds16(ga + koff + 2048, &ldsA[buf][0] + 2048 + w * 512);
    gld_lds16(gb + koff, &ldsB[buf][0] + w * 512);
    gld_lds16(gb + koff + 2048, &ldsB[buf][0] + 2048 + w * 512);
  };
  auto compute = [&](int buf) {
    const short* sA = &ldsA[buf][0];
    const short* sB = &ldsB[buf][0];
    const short8 af0 = *(const short8*)&sA[(w * 64 + lane) * 8];
    const short8 af1 = *(const short8*)&sA[2048 + (w * 64 + lane) * 8];
#pragma unroll
    for (int j = 0; j < 4; j++) {
      const short8 bf0 = *(const short8*)&sB[(j * 64 + lane) * 8];
      const short8 bf1 = *(const short8*)&sB[2048 + (j * 64 + lane) * 8];
      acc[j] = __builtin_amdgcn_mfma_f32_16x16x32_bf16(af0, bf0, acc[j], 0, 0, 0);
      acc[j] = __builtin_amdgcn_mfma_f32_16x16x32_bf16(af1, bf1, acc[j], 0, 0, 0);
    }
  };

  stage(0, 0);
  stage(1, 1);
#pragma unroll
  for (int i = 0; i < 14; ++i) {
    WAITVM(4);
    sbar();
    stage(i + 2, (i + 2) % 3);
    compute(i % 3);
  }
  WAITVM(4);
  sbar();
  compute(14 % 3);
  WAITVM(0);
  sbar();
  compute(15 % 3);

#pragma unroll
  for (int j = 0; j < 4; j++)
#pragma unroll
    for (int r = 0; r < 4; r++) {
      const int gr = rt * 64 + w * 16 + lg * 4 + r;
      const int gc = ct * 64 + j * 16 + l15;
      Of[(size_t)gr * 1024 + gc] = acc[j][r];
    }
}

extern "C" void kernel_launch(void* const* d_in, const int* in_sizes, int n_in,
                              void* d_out, int out_size, void* d_ws, size_t ws_size,
                              hipStream_t stream) {
  const float* x   = (const float*)d_in[0];   // fp32 (2,1024,1024)
  const float* ctx = (const float*)d_in[1];   // fp32 (2,2048,1024)
  const unsigned char* mask = (const unsigned char*)d_in[2];  // (2,1024,2048)
  const float* Wq  = (const float*)d_in[3];
  const float* Wkv = (const float*)d_in[4];
  const float* bkv = (const float*)d_in[5];
  const float* Wo  = (const float*)d_in[6];
  float* out = (float*)d_out;                 // FP32 (2,1024,1024)

  char* wsb = (char*)d_ws;
  short* qws  = (short*)(wsb);                        // bf16 Q*scl  4MB @0
  short* kws  = (short*)(wsb + (4u << 20));           // bf16 K      8MB @4M
  short* vtws = (short*)(wsb + (12u << 20));          // bf16 V^T    8MB @12M
  short* wqb  = (short*)(wsb + (20u << 20));          // bf16 Wq(T)  2MB @20M
  short* wkvb = (short*)(wsb + (22u << 20));          // bf16 Wkv(T) 4MB @22M
  short* wob  = (short*)(wsb + (26u << 20));          // bf16 Wo(T)  2MB @26M
  unsigned long long* pmws = (unsigned long long*)(wsb + (28u << 20));  // .5MB
  float* opart = (float*)(wsb + (29u << 20));         // fp32 2x8MB  16MB @29M
  float* lpart = (float*)(wsb + (45u << 20));         // fp32 .25MB  @45M
  short* xb   = (short*)(wsb + (29u << 20));          // bf16 x(T)   4MB @29M
  short* ctxb = (short*)(wsb + (33u << 20));          // bf16 ctx(T) 8MB @33M
  short* ao = (short*)(wsb + (20u << 20));  // bf16 AO(T) 4MB (reuses wqb/wkvb)

  prep<<<2048, 256, 0, stream>>>(mask, pmws, Wq, Wkv, Wo, x, ctx,
                                 wqb, wkvb, wob, xb, ctxb);
  qkv_gemm<<<640, 256, 0, stream>>>(xb, ctxb, wqb, wkvb, bkv, qws, kws, vtws);
  attn_split<<<512, 512, 0, stream>>>(qws, kws, vtws, (const unsigned int*)pmws,
                                      opart, lpart);
  combine<<<2048, 256, 0, stream>>>(opart, lpart, ao);
  o_gemm<<<512, 256, 0, stream>>>(ao, wob, out);
}

// Round 11
// 208.366 us; speedup vs baseline: 1.0031x; 1.0031x over previous
//
#include <hip/hip_runtime.h>

// ============================================================================
// ROUND 23: fold split-K INSIDE attn -> combine kernel + opart/lpart GONE.
//  - attn_fused: 512 blocks x 512 threads (unchanged 16 waves/CU). QBLK=64,
//    waves 0-3 handle m in [0,1024), waves 4-7 m in [1024,2048) (KVBLK=64,
//    16 phases/group). Inner compute = R22's VERIFIED computeC4; phase
//    sequencing = R17's VERIFIED 2-barrier/WAITVM(4) pattern. Epilogue:
//    group-1 partials -> LDS, group-0 adds, divides by (l0+l1) and writes
//    final bf16 ao in the off64 tiled layout (same addresses + same
//    half+half fp32 add order as combine -> numerics preserved).
//    Removes 16MB fp32 opart writes + 16.25MB reads + 4MB writes + 1 launch.
//  - prep (R21 output-linear), qkv_gemm (R15 best), o_gemm (R17) unchanged.
// ============================================================================

typedef __attribute__((ext_vector_type(8))) short short8;
typedef __attribute__((ext_vector_type(4))) short short4v;
typedef __attribute__((ext_vector_type(4))) float f32x4;
typedef __attribute__((ext_vector_type(4))) int int4v;

#define SCL2E 0.18033688011112042592f /* (1/8) * log2(e) */

__device__ __forceinline__ short f2bf(float f) {
  unsigned u = __float_as_uint(f);
  u += 0x7fffu + ((u >> 16) & 1u);
  return (short)(u >> 16);
}
__device__ __forceinline__ int cvt_pk_bf16(float a, float b) {
  int r;
  asm("v_cvt_pk_bf16_f32 %0, %1, %2" : "=v"(r) : "v"(a), "v"(b));
  return r;
}
__device__ __forceinline__ void gld_lds16(const void* gp, void* lp) {
  __builtin_amdgcn_global_load_lds(
      (const __attribute__((address_space(1))) unsigned int*)gp,
      (__attribute__((address_space(3))) unsigned int*)lp, 16, 0, 0);
}
__device__ __forceinline__ void sbar() {
  __builtin_amdgcn_sched_barrier(0);
  __builtin_amdgcn_s_barrier();
  __builtin_amdgcn_sched_barrier(0);
}
#define WAITVM(N) asm volatile("s_waitcnt vmcnt(" #N ")" ::: "memory")

__device__ __forceinline__ void pipesync() {
  asm volatile("s_waitcnt vmcnt(0) lgkmcnt(0)" ::: "memory");
  __builtin_amdgcn_sched_barrier(0);
  __builtin_amdgcn_s_barrier();
  __builtin_amdgcn_sched_barrier(0);
}
__device__ __forceinline__ short4v cvt4(float4 v) {
  short4v o;
  o[0] = f2bf(v.x); o[1] = f2bf(v.y); o[2] = f2bf(v.z); o[3] = f2bf(v.w);
  return o;
}
// 64-row tiled layout: element (row,k) -> frag-set-ordered offset (shorts).
__device__ __forceinline__ size_t off64(int row, int k) {
  return ((size_t)(((row >> 6) * 32 + (k >> 5)) * 4 + ((row >> 4) & 3)) << 9) +
         (((((k >> 3) & 3) * 16 + (row & 15)) << 3) + (k & 7));
}

// ---------------------------------------------------------------------------
// prep (R21): mask bit-pack + fp32->bf16 tiled conversion, OUTPUT-LINEAR.
// ---------------------------------------------------------------------------
__global__ __launch_bounds__(256) void prep(
    const unsigned char* __restrict__ mask, unsigned long long* __restrict__ pm,
    const float* __restrict__ Wq, const float* __restrict__ Wkv,
    const float* __restrict__ Wo, const float* __restrict__ x,
    const float* __restrict__ ctx, short* __restrict__ wqb,
    short* __restrict__ wkvb, short* __restrict__ wob,
    short* __restrict__ xb, short* __restrict__ ctxb) {
  const int row = blockIdx.x;
  const int wave = threadIdx.x >> 6, lane = threadIdx.x & 63;
  const unsigned char p8 = mask[lane * 4 + 1];
  const int p32 = ((const int*)mask)[lane * 2 + 1];
  const int shift =
      (__ballot(p8 != 0) != 0ull) ? 0 : ((__ballot(p32 != 0) != 0ull) ? 2 : 3);
  const size_t mbase = ((size_t)row * 2048) << shift;
#pragma unroll
  for (int j = 0; j < 8; j++) {
    const int c = wave * 512 + j * 64 + lane;
    const unsigned long long bits = __ballot(mask[mbase + ((size_t)c << shift)] != 0);
    if (lane == 0) pm[(size_t)row * 32 + wave * 8 + j] = bits;
  }
  const int gid = blockIdx.x * 256 + threadIdx.x;  // [0, 524288)
  {  // xb: 2048x1024, 128-tiled
    const int T = gid * 4;
    const int j = T & 4, r15 = (T >> 3) & 15, q = (T >> 7) & 3;
    const int f = (T >> 9) & 7, kc = (T >> 12) & 31, rt = T >> 17;
    const int r = rt * 128 + f * 16 + r15, k = kc * 32 + q * 8 + j;
    *(short4v*)(xb + T) = cvt4(*(const float4*)(x + (((size_t)r) << 10) + k));
  }
#pragma unroll
  for (int it = 0; it < 2; it++) {  // ctxb: 4096x1024, 128-tiled
    const int T = (gid + it * 524288) * 4;
    const int j = T & 4, r15 = (T >> 3) & 15, q = (T >> 7) & 3;
    const int f = (T >> 9) & 7, kc = (T >> 12) & 31, rt = T >> 17;
    const int r = rt * 128 + f * 16 + r15, k = kc * 32 + q * 8 + j;
    *(short4v*)(ctxb + T) = cvt4(*(const float4*)(ctx + (((size_t)r) << 10) + k));
  }
  {  // wkvb: 2048x1024, 128-tiled
    const int T = gid * 4;
    const int j = T & 4, r15 = (T >> 3) & 15, q = (T >> 7) & 3;
    const int f = (T >> 9) & 7, kc = (T >> 12) & 31, rt = T >> 17;
    const int r = rt * 128 + f * 16 + r15, k = kc * 32 + q * 8 + j;
    *(short4v*)(wkvb + T) = cvt4(*(const float4*)(Wkv + (((size_t)r) << 10) + k));
  }
  if (gid < 262144) {  // Wq 128-tiled; Wo 64-tiled
    const int T = gid * 4;
    {
      const int j = T & 4, r15 = (T >> 3) & 15, q = (T >> 7) & 3;
      const int f = (T >> 9) & 7, kc = (T >> 12) & 31, rt = T >> 17;
      const int r = rt * 128 + f * 16 + r15, k = kc * 32 + q * 8 + j;
      *(short4v*)(wqb + T) = cvt4(*(const float4*)(Wq + (((size_t)r) << 10) + k));
    }
    {
      const int j = T & 4, r15 = (T >> 3) & 15, q = (T >> 7) & 3;
      const int f = (T >> 9) & 3, kc = (T >> 11) & 31, rt = T >> 16;
      const int r = rt * 64 + f * 16 + r15, k = kc * 32 + q * 8 + j;
      *(short4v*)(wob + T) = cvt4(*(const float4*)(Wo + (((size_t)r) << 10) + k));
    }
  }
}

// ---------------------------------------------------------------------------
// qkv_gemm (R15 exact, measured best): 128x128 tile, BK=32, NBUF=3 (48KB),
// counted vmcnt(4), one barrier per phase, XCD-chunked swizzle, 3 blocks/CU.
// ---------------------------------------------------------------------------
__global__ __launch_bounds__(256, 3)
void qkv_gemm(const short* __restrict__ xb, const short* __restrict__ ctxb,
              const short* __restrict__ wqb, const short* __restrict__ wkvb,
              const float* __restrict__ bias, short* __restrict__ qws,
              short* __restrict__ kws, short* __restrict__ vtws) {
  __shared__ __align__(16) short ldsA[3][4096];
  __shared__ __align__(16) short ldsB[3][4096];
  const int tid = threadIdx.x;
  const int wave = tid >> 6, lane = tid & 63;
  const int l15 = lane & 15, lg = lane >> 4;
  const int bx0 = blockIdx.x;
  const int bx = (bx0 & 7) * 80 + (bx0 >> 3);
  const bool isKV = bx < 512;
  const int rt = isKV ? (bx >> 4) : ((bx - 512) >> 3);
  const int ct = isKV ? (bx & 15) : ((bx - 512) & 7);
  const short* Amat = isKV ? ctxb : xb;
  const short* Bw = isKV ? wkvb : wqb;
  const int wr = wave >> 1, wc = wave & 1;

  f32x4 acc[4][4];
#pragma unroll
  for (int i = 0; i < 4; i++)
#pragma unroll
    for (int j = 0; j < 4; j++) acc[i][j] = (f32x4){0.f, 0.f, 0.f, 0.f};

  const short* ga0 = Amat + (size_t)rt * 131072 + wave * 512 + lane * 8;
  const short* ga1 = ga0 + 2048;
  const short* gb0 = Bw + (size_t)ct * 131072 + wave * 512 + lane * 8;
  const short* gb1 = gb0 + 2048;

  auto stage = [&](int kk, int buf) {
    const size_t koff = (size_t)kk * 4096;
    short* dA = &ldsA[buf][0];
    short* dB = &ldsB[buf][0];
    gld_lds16(ga0 + koff, dA + wave * 512);
    gld_lds16(ga1 + koff, dA + (wave + 4) * 512);
    gld_lds16(gb0 + koff, dB + wave * 512);
    gld_lds16(gb1 + koff, dB + (wave + 4) * 512);
  };
  auto compute = [&](int buf) {
    const short* sA = &ldsA[buf][0];
    const short* sB = &ldsB[buf][0];
    short8 af[4], bfr[4];
#pragma unroll
    for (int t = 0; t < 4; t++)
      af[t] = *(const short8*)&sA[((wr * 4 + t) * 64 + lane) * 8];
#pragma unroll
    for (int t = 0; t < 4; t++)
      bfr[t] = *(const short8*)&sB[((wc * 4 + t) * 64 + lane) * 8];
#pragma unroll
    for (int i = 0; i < 4; i++)
#pragma unroll
      for (int j = 0; j < 4; j++)
        acc[i][j] =
            __builtin_amdgcn_mfma_f32_16x16x32_bf16(af[i], bfr[j], acc[i][j], 0, 0, 0);
  };

  stage(0, 0);
  stage(1, 1);
  int cur = 0, nxt = 2;
  for (int i = 0; i < 30; ++i) {
    WAITVM(4);
    sbar();
    stage(i + 2, nxt);
    compute(cur);
    cur = (cur == 2) ? 0 : cur + 1;
    nxt = (nxt == 2) ? 0 : nxt + 1;
  }
  WAITVM(4);
  sbar();
  compute(cur);
  cur = (cur == 2) ? 0 : cur + 1;
  WAITVM(0);
  sbar();
  compute(cur);

#pragma unroll
  for (int i = 0; i < 4; i++)
#pragma unroll
    for (int j = 0; j < 4; j++)
#pragma unroll
      for (int r = 0; r < 4; r++) {
        const int gr = rt * 128 + wr * 64 + i * 16 + lg * 4 + r;
        const int gc = ct * 128 + wc * 64 + j * 16 + l15;
        float v = acc[i][j][r];
        if (isKV) {
          v += bias[gc];
          const int b = gr >> 11, m = gr & 2047;
          const int kv = gc >> 10, hh = (gc >> 6) & 15, d = gc & 63;
          if (kv == 0)
            kws[((((size_t)b * 16 + hh) * 2048 + m) << 6) + d] = f2bf(v);
          else {
            // permuted V^T column so attn's in-register P-frag order matches
            const int mp = (m & ~31) | (((m >> 2) & 3) << 3) |
                           (((m >> 4) & 1) << 2) | (m & 3);
            vtws[(((size_t)b * 16 + hh) * 64 + d) * 2048 + mp] = f2bf(v);
          }
        } else {
          const int b = gr >> 10, n = gr & 1023, hh = gc >> 6, d = gc & 63;
          qws[((((size_t)b * 16 + hh) * 1024 + n) << 6) + d] = f2bf(v * SCL2E);
        }
      }
}

// ---------------------------------------------------------------------------
// attn_fused (R23): split-K x2 INSIDE the block. 512 blocks x 512 threads.
// QBLK=64 (qt 0..15); waves 0-3 = m-group 0 [0,1024), waves 4-7 = group 1
// [1024,2048). KVBLK=64, 16 phases per group, R17's 2-barrier/WAITVM(4)
// pattern, R22's verified computeC4 math. Epilogue: group-1 partials via
// LDS, group-0 adds, divides, writes final bf16 ao (off64-tiled) directly.
// LDS: ldsK[2][2grp*8KB] + ldsV same = 64KB -> 2 blocks/CU (16 waves/CU).
// ---------------------------------------------------------------------------
__global__ __launch_bounds__(512, 4)
void attn_fused(const short* __restrict__ Qg, const short* __restrict__ Kg,
                const short* __restrict__ Vtg,
                const unsigned int* __restrict__ pm,
                short* __restrict__ aoT) {
  __shared__ __align__(16) short ldsK[2][8192];  // [buf][g*4096 + f*512]
  __shared__ __align__(16) short ldsV[2][8192];
  const int tid = threadIdx.x;
  const int w = tid >> 6, lane = tid & 63;
  const int l15 = lane & 15, lg = lane >> 4;
  const int g = w >> 2, ww = w & 3;
  const int bx = blockIdx.x;
  const int bhid = bx & 31, qt = bx >> 5;
  const int b = bhid >> 4, h = bhid & 15;
  const int n0 = qt * 64, m_base = g * 1024;
  const size_t bh = (size_t)b * 16 + h;
  const short* Qb = Qg + (bh * 1024 + n0) * 64;
  const short* Kb = Kg + (bh << 17);
  const short* Vb = Vtg + (bh << 17);
  // mask words for row n = n0+ww*16+l15 (broadcast across lg), group offset
  const unsigned int* pmw =
      pm + ((size_t)(b * 1024 + n0 + ww * 16 + l15) << 6) + (m_base >> 5);

  // Preload this group's 32 mask words (16 phases x 2) as 8 uint4.
  uint4 mku[8];
#pragma unroll
  for (int i = 0; i < 8; i++) mku[i] = *(const uint4*)(pmw + i * 4);

  // stage tile c of this group's m-range: wave ww does m-subtile t=ww (K)
  // and d-block vt=ww (V); 2 loads each (d-half / m-half).
  auto stageKV = [&](int c, int buf) {
    const int m0 = m_base + c * 64;
    short* dK = &ldsK[buf][g * 4096];
    short* dV = &ldsV[buf][g * 4096];
#pragma unroll
    for (int ii = 0; ii < 2; ii++) {
      gld_lds16(Kb + (size_t)(m0 + ww * 16 + l15) * 64 + ii * 32 + lg * 8,
                dK + (ww * 2 + ii) * 512);
      gld_lds16(Vb + (size_t)(ww * 16 + l15) * 2048 + (m0 + ii * 32 + lg * 8),
                dV + (ww * 2 + ii) * 512);
    }
  };

  // Prologue: Q (8 frag-sets: 64 rows x 64 d) -> ldsV[1][0..4096) staged by
  // group 0; tile 0 of BOTH groups -> buf 0.
  if (g == 0) {
#pragma unroll
    for (int ii = 0; ii < 2; ii++)
      gld_lds16(Qb + (size_t)(ww * 16 + l15) * 64 + ii * 32 + lg * 8,
                &ldsV[1][(ww * 2 + ii) * 512]);
  }
  stageKV(0, 0);
  pipesync();
  short8 qf[2];
#pragma unroll
  for (int ks = 0; ks < 2; ks++)
    qf[ks] = *(const short8*)&ldsV[1][((ww * 2 + ks) * 64 + lane) * 8];
  // All waves must finish reading Q before stage(1) overwrites ldsV[1].
  asm volatile("s_waitcnt lgkmcnt(0)" ::: "memory");
  sbar();

  short8 onesf;
#pragma unroll
  for (int i = 0; i < 8; i++) onesf[i] = (short)0x3F80;  // bf16 1.0

  f32x4 o[4], lacc;
#pragma unroll
  for (int ct = 0; ct < 4; ct++) o[ct] = (f32x4){0.f, 0.f, 0.f, 0.f};
  lacc = (f32x4){0.f, 0.f, 0.f, 0.f};
  const int sb = lg * 4;

  // R22-verified computeC4 (KVBLK=64): 8 QK MFMA, mask+exp2, cvt_pk,
  // 8 PV + 2 lacc MFMA. Reads this group's LDS region.
  auto computeC4 = [&](unsigned int mw0, unsigned int mw1, int buf) {
    const short* sK = &ldsK[buf][g * 4096];
    const short* sV = &ldsV[buf][g * 4096];
    f32x4 s[4];
#pragma unroll
    for (int t = 0; t < 4; t++) s[t] = (f32x4){0.f, 0.f, 0.f, 0.f};
#pragma unroll
    for (int t = 0; t < 4; t++)
#pragma unroll
      for (int ks = 0; ks < 2; ks++) {
        const short8 kf = *(const short8*)&sK[((t * 2 + ks) * 64 + lane) * 8];
        s[t] = __builtin_amdgcn_mfma_f32_16x16x32_bf16(kf, qf[ks], s[t], 0, 0, 0);
      }
    int4v pw4[2];
#pragma unroll
    for (int t = 0; t < 4; t++) {
      const unsigned int mw = (t >> 1) ? mw1 : mw0;
      float p[4];
#pragma unroll
      for (int r = 0; r < 4; r++) {
        const bool att = (mw >> (((t & 1) << 4) + sb + r)) & 1;
        p[r] = exp2f(att ? s[t][r] : -1e30f);
      }
      pw4[t >> 1][(t & 1) * 2] = cvt_pk_bf16(p[0], p[1]);
      pw4[t >> 1][(t & 1) * 2 + 1] = cvt_pk_bf16(p[2], p[3]);
    }
#pragma unroll
    for (int ks2 = 0; ks2 < 2; ks2++) {
      const short8 pf = __builtin_bit_cast(short8, pw4[ks2]);
#pragma unroll
      for (int ct = 0; ct < 4; ct++) {
        const short8 vf = *(const short8*)&sV[((ct * 2 + ks2) * 64 + lane) * 8];
        o[ct] = __builtin_amdgcn_mfma_f32_16x16x32_bf16(pf, vf, o[ct], 0, 0, 0);
      }
      lacc = __builtin_amdgcn_mfma_f32_16x16x32_bf16(pf, onesf, lacc, 0, 0, 0);
    }
  };

  // Main loop (R17 pattern): stage(c+1) -> WAITVM(4) -> bar -> compute(c)
  // -> bar. Tile c+1 stays in flight across the whole phase.
#pragma unroll
  for (int c = 0; c < 16; c++) {
    if (c + 1 < 16) {
      stageKV(c + 1, (c + 1) & 1);
      WAITVM(4);
    } else {
      WAITVM(0);
    }
    sbar();
    const uint4 mk = mku[c >> 1];
    const unsigned int mw0 = (c & 1) ? mk.z : mk.x;
    const unsigned int mw1 = (c & 1) ? mk.w : mk.y;
    computeC4(mw0, mw1, c & 1);
    sbar();
  }

  // Epilogue: cross-group reduction via LDS, then divide + tiled bf16 write.
  float* fO = (float*)&ldsK[0][0];  // 4096 f32 (16KB of the 32KB ldsK)
  float* fL = (float*)&ldsV[0][0];  // 1024 f32
  if (g == 1) {
#pragma unroll
    for (int ct = 0; ct < 4; ct++)
#pragma unroll
      for (int r = 0; r < 4; r++)
        fO[(ww * 64 + lane) * 16 + ct * 4 + r] = o[ct][r];
#pragma unroll
    for (int r = 0; r < 4; r++) fL[(ww * 64 + lane) * 4 + r] = lacc[r];
  }
  asm volatile("s_waitcnt lgkmcnt(0)" ::: "memory");
  sbar();
  if (g == 0) {
    float inv[4];
#pragma unroll
    for (int r = 0; r < 4; r++) {
      const float lt = lacc[r] + fL[(ww * 64 + lane) * 4 + r];
      inv[r] = 1.f / fmaxf(lt, 1e-30f);
    }
#pragma unroll
    for (int ct = 0; ct < 4; ct++)
#pragma unroll
      for (int r = 0; r < 4; r++) {
        const float v =
            (o[ct][r] + fO[(ww * 64 + lane) * 16 + ct * 4 + r]) * inv[r];
        const int row = b * 1024 + n0 + ww * 16 + lg * 4 + r;
        const int col = h * 64 + ct * 16 + l15;
        aoT[off64(row, col)] = f2bf(v);
      }
  }
}

// ---------------------------------------------------------------------------
// o_gemm (R17, unchanged): 64x64 tiles, BK=64 (16 phases x 8 MFMA),
// 512 blocks, NBUF=3 (48KB LDS, 3 blocks/CU), counted vmcnt(4), XCD swizzle.
// ---------------------------------------------------------------------------
__global__ __launch_bounds__(256, 3)
void o_gemm(const short* __restrict__ aoT, const short* __restrict__ wobT,
            float* __restrict__ Of) {
  __shared__ __align__(16) short ldsA[3][4096];
  __shared__ __align__(16) short ldsB[3][4096];
  const int tid = threadIdx.x;
  const int w = tid >> 6, lane = tid & 63;
  const int l15 = lane & 15, lg = lane >> 4;
  const int bx0 = blockIdx.x;
  const int bx = (bx0 & 7) * 64 + (bx0 >> 3);
  const int rt = bx >> 4, ct = bx & 15;

  f32x4 acc[4];
#pragma unroll
  for (int j = 0; j < 4; j++) acc[j] = (f32x4){0.f, 0.f, 0.f, 0.f};

  const short* ga = aoT + (size_t)rt * 65536 + w * 512 + lane * 8;
  const short* gb = wobT + (size_t)ct * 65536 + w * 512 + lane * 8;

  auto stage = [&](int t, int buf) {
    const size_t koff = (size_t)t * 4096;
    gld_lds16(ga + koff, &ldsA[buf][0] + w * 512);
    gld_lds16(ga + koff + 2048, &ldsA[buf][0] + 2048 + w * 512);
    gld_lds16(gb + koff, &ldsB[buf][0] + w * 512);
    gld_lds16(gb + koff + 2048, &ldsB[buf][0] + 2048 + w * 512);
  };
  auto compute = [&](int buf) {
    const short* sA = &ldsA[buf][0];
    const short* sB = &ldsB[buf][0];
    const short8 af0 = *(const short8*)&sA[(w * 64 + lane) * 8];
    const short8 af1 = *(const short8*)&sA[2048 + (w * 64 + lane) * 8];
#pragma unroll
    for (int j = 0; j < 4; j++) {
      const short8 bf0 = *(const short8*)&sB[(j * 64 + lane) * 8];
      const short8 bf1 = *(const short8*)&sB[2048 + (j * 64 + lane) * 8];
      acc[j] = __builtin_amdgcn_mfma_f32_16x16x32_bf16(af0, bf0, acc[j], 0, 0, 0);
      acc[j] = __builtin_amdgcn_mfma_f32_16x16x32_bf16(af1, bf1, acc[j], 0, 0, 0);
    }
  };

  stage(0, 0);
  stage(1, 1);
#pragma unroll
  for (int i = 0; i < 14; ++i) {
    WAITVM(4);
    sbar();
    stage(i + 2, (i + 2) % 3);
    compute(i % 3);
  }
  WAITVM(4);
  sbar();
  compute(14 % 3);
  WAITVM(0);
  sbar();
  compute(15 % 3);

#pragma unroll
  for (int j = 0; j < 4; j++)
#pragma unroll
    for (int r = 0; r < 4; r++) {
      const int gr = rt * 64 + w * 16 + lg * 4 + r;
      const int gc = ct * 64 + j * 16 + l15;
      Of[(size_t)gr * 1024 + gc] = acc[j][r];
    }
}

extern "C" void kernel_launch(void* const* d_in, const int* in_sizes, int n_in,
                              void* d_out, int out_size, void* d_ws, size_t ws_size,
                              hipStream_t stream) {
  const float* x   = (const float*)d_in[0];   // fp32 (2,1024,1024)
  const float* ctx = (const float*)d_in[1];   // fp32 (2,2048,1024)
  const unsigned char* mask = (const unsigned char*)d_in[2];  // (2,1024,2048)
  const float* Wq  = (const float*)d_in[3];
  const float* Wkv = (const float*)d_in[4];
  const float* bkv = (const float*)d_in[5];
  const float* Wo  = (const float*)d_in[6];
  float* out = (float*)d_out;                 // FP32 (2,1024,1024)

  char* wsb = (char*)d_ws;
  short* qws  = (short*)(wsb);                        // bf16 Q*scl  4MB @0
  short* kws  = (short*)(wsb + (4u << 20));           // bf16 K      8MB @4M
  short* vtws = (short*)(wsb + (12u << 20));          // bf16 V^T    8MB @12M
  short* wqb  = (short*)(wsb + (20u << 20));          // bf16 Wq(T)  2MB @20M
  short* wkvb = (short*)(wsb + (22u << 20));          // bf16 Wkv(T) 4MB @22M
  short* wob  = (short*)(wsb + (26u << 20));          // bf16 Wo(T)  2MB @26M
  unsigned long long* pmws = (unsigned long long*)(wsb + (28u << 20));  // .5MB
  short* xb   = (short*)(wsb + (29u << 20));          // bf16 x(T)   4MB @29M
  short* ctxb = (short*)(wsb + (33u << 20));          // bf16 ctx(T) 8MB @33M
  short* ao = (short*)(wsb + (41u << 20));            // bf16 AO(T)  4MB @41M

  prep<<<2048, 256, 0, stream>>>(mask, pmws, Wq, Wkv, Wo, x, ctx,
                                 wqb, wkvb, wob, xb, ctxb);
  qkv_gemm<<<640, 256, 0, stream>>>(xb, ctxb, wqb, wkvb, bkv, qws, kws, vtws);
  attn_fused<<<512, 512, 0, stream>>>(qws, kws, vtws,
                                      (const unsigned int*)pmws, ao);
  o_gemm<<<512, 256, 0, stream>>>(ao, wob, out);
}

// Round 12
// 202.693 us; speedup vs baseline: 1.0312x; 1.0280x over previous
//
#include <hip/hip_runtime.h>

// ============================================================================
// ROUND 24 = R21 base (measured best, 205.35us) + two independent fixes:
//  - prep: LDS-TRANSPOSE conversion. R21 gathered scattered 32B segments
//    from rows 4KB apart (~2x read over-fetch on 44MB). Now each block
//    stages a 64x128 fp32 chunk: coalesced 512B row reads -> padded LDS
//    (136-short rows, conflict-light) -> contiguous 1KB tiled writes.
//    Output offset base+t*8 == off128/off64(row,k) exactly -> bit-identical.
//  - attn_split: + s_setprio(1/0) around QK and PV MFMA clusters (T5,
//    measured +4-7% on attn). Structure otherwise R17/R21-exact.
//  - qkv_gemm (R15 best), combine (R21 output-linear), o_gemm (R17)
//    unchanged. R23's fused attn reverted (73us, +295K bank conflicts).
// ============================================================================

typedef __attribute__((ext_vector_type(8))) short short8;
typedef __attribute__((ext_vector_type(4))) short short4v;
typedef __attribute__((ext_vector_type(4))) float f32x4;
typedef __attribute__((ext_vector_type(4))) int int4v;

#define SCL2E 0.18033688011112042592f /* (1/8) * log2(e) */

__device__ __forceinline__ short f2bf(float f) {
  unsigned u = __float_as_uint(f);
  u += 0x7fffu + ((u >> 16) & 1u);
  return (short)(u >> 16);
}
__device__ __forceinline__ int cvt_pk_bf16(float a, float b) {
  int r;
  asm("v_cvt_pk_bf16_f32 %0, %1, %2" : "=v"(r) : "v"(a), "v"(b));
  return r;
}
__device__ __forceinline__ void gld_lds16(const void* gp, void* lp) {
  __builtin_amdgcn_global_load_lds(
      (const __attribute__((address_space(1))) unsigned int*)gp,
      (__attribute__((address_space(3))) unsigned int*)lp, 16, 0, 0);
}
__device__ __forceinline__ void sbar() {
  __builtin_amdgcn_sched_barrier(0);
  __builtin_amdgcn_s_barrier();
  __builtin_amdgcn_sched_barrier(0);
}
#define WAITVM(N) asm volatile("s_waitcnt vmcnt(" #N ")" ::: "memory")

__device__ __forceinline__ void pipesync() {
  asm volatile("s_waitcnt vmcnt(0) lgkmcnt(0)" ::: "memory");
  __builtin_amdgcn_sched_barrier(0);
  __builtin_amdgcn_s_barrier();
  __builtin_amdgcn_sched_barrier(0);
}
__device__ __forceinline__ short4v cvt4(float4 v) {
  short4v o;
  o[0] = f2bf(v.x); o[1] = f2bf(v.y); o[2] = f2bf(v.z); o[3] = f2bf(v.w);
  return o;
}
// 64-row tiled layout (combine epilogue only).
__device__ __forceinline__ size_t off64(int row, int k) {
  return ((size_t)(((row >> 6) * 32 + (k >> 5)) * 4 + ((row >> 4) & 3)) << 9) +
         (((((k >> 3) & 3) * 16 + (row & 15)) << 3) + (k & 7));
}

// ---------------------------------------------------------------------------
// prep (R24): mask bit-pack (all 2048 blocks) + LDS-transpose fp32->bf16
// tiled conversion (blocks 0..1279, one 64x128 chunk each).
//  read pass p: thread t loads float4 at (R0+p*8+(t>>5), C0+(t&31)*4) —
//    coalesced 512B/row — converts, stores 8B to padded LDS [64][136].
//  write pass kc_l: thread t reads 16B at LDS[(t>>6)*16+(t&15)]
//    [kc_l*32+((t>>4)&3)*8], writes contiguous 16B at dst + base + t*8,
//    where base+t*8 == off128/off64(row,k) for the decoded (row,k).
// ---------------------------------------------------------------------------
__global__ __launch_bounds__(256) void prep(
    const unsigned char* __restrict__ mask, unsigned long long* __restrict__ pm,
    const float* __restrict__ Wq, const float* __restrict__ Wkv,
    const float* __restrict__ Wo, const float* __restrict__ x,
    const float* __restrict__ ctx, short* __restrict__ wqb,
    short* __restrict__ wkvb, short* __restrict__ wob,
    short* __restrict__ xb, short* __restrict__ ctxb) {
  __shared__ __align__(16) short lds[64][136];
  const int row = blockIdx.x;
  const int wave = threadIdx.x >> 6, lane = threadIdx.x & 63;
  const unsigned char p8 = mask[lane * 4 + 1];
  const int p32 = ((const int*)mask)[lane * 2 + 1];
  const int shift =
      (__ballot(p8 != 0) != 0ull) ? 0 : ((__ballot(p32 != 0) != 0ull) ? 2 : 3);
  const size_t mbase = ((size_t)row * 2048) << shift;
#pragma unroll
  for (int j = 0; j < 8; j++) {
    const int c = wave * 512 + j * 64 + lane;
    const unsigned long long bits = __ballot(mask[mbase + ((size_t)c << shift)] != 0);
    if (lane == 0) pm[(size_t)row * 32 + wave * 8 + j] = bits;
  }

  const int bid = blockIdx.x;
  if (bid >= 1280) return;  // uniform per-block branch
  const float* src;
  short* dst;
  int cb;
  bool t64 = false;
  if (bid < 256) {
    src = x; dst = xb; cb = bid;
  } else if (bid < 768) {
    src = ctx; dst = ctxb; cb = bid - 256;
  } else if (bid < 1024) {
    src = Wkv; dst = wkvb; cb = bid - 768;
  } else if (bid < 1152) {
    src = Wq; dst = wqb; cb = bid - 1024;
  } else {
    src = Wo; dst = wob; cb = bid - 1152; t64 = true;
  }
  const int R0 = (cb >> 3) * 64, C0 = (cb & 7) * 128;
  const int t = threadIdx.x;
#pragma unroll
  for (int p = 0; p < 8; p++) {
    const int r = R0 + p * 8 + (t >> 5), c = C0 + (t & 31) * 4;
    const float4 v = *(const float4*)(src + (size_t)r * 1024 + c);
    *(short4v*)&lds[p * 8 + (t >> 5)][(t & 31) * 4] = cvt4(v);
  }
  __syncthreads();
  const int rt = t64 ? (R0 >> 6) : (R0 >> 7);
  const int f0 = t64 ? 0 : ((R0 >> 6) & 1) * 4;
  const int fl = t >> 6, q = (t >> 4) & 3, r15 = t & 15;
  const int lrow = fl * 16 + r15;
#pragma unroll
  for (int kc_l = 0; kc_l < 4; kc_l++) {
    const int kc = (C0 >> 5) + kc_l;
    const size_t base = t64 ? ((size_t)((rt * 32 + kc) * 4)) * 512
                            : ((size_t)((rt * 32 + kc) * 8 + f0)) * 512;
    const short8 vv = *(const short8*)&lds[lrow][kc_l * 32 + q * 8];
    *(short8*)(dst + base + t * 8) = vv;
  }
}

// ---------------------------------------------------------------------------
// qkv_gemm (R15 exact, measured best): 128x128 tile, BK=32, NBUF=3 (48KB),
// counted vmcnt(4), one barrier per phase, XCD-chunked swizzle, 3 blocks/CU.
// ---------------------------------------------------------------------------
__global__ __launch_bounds__(256, 3)
void qkv_gemm(const short* __restrict__ xb, const short* __restrict__ ctxb,
              const short* __restrict__ wqb, const short* __restrict__ wkvb,
              const float* __restrict__ bias, short* __restrict__ qws,
              short* __restrict__ kws, short* __restrict__ vtws) {
  __shared__ __align__(16) short ldsA[3][4096];
  __shared__ __align__(16) short ldsB[3][4096];
  const int tid = threadIdx.x;
  const int wave = tid >> 6, lane = tid & 63;
  const int l15 = lane & 15, lg = lane >> 4;
  const int bx0 = blockIdx.x;
  const int bx = (bx0 & 7) * 80 + (bx0 >> 3);
  const bool isKV = bx < 512;
  const int rt = isKV ? (bx >> 4) : ((bx - 512) >> 3);
  const int ct = isKV ? (bx & 15) : ((bx - 512) & 7);
  const short* Amat = isKV ? ctxb : xb;
  const short* Bw = isKV ? wkvb : wqb;
  const int wr = wave >> 1, wc = wave & 1;

  f32x4 acc[4][4];
#pragma unroll
  for (int i = 0; i < 4; i++)
#pragma unroll
    for (int j = 0; j < 4; j++) acc[i][j] = (f32x4){0.f, 0.f, 0.f, 0.f};

  const short* ga0 = Amat + (size_t)rt * 131072 + wave * 512 + lane * 8;
  const short* ga1 = ga0 + 2048;
  const short* gb0 = Bw + (size_t)ct * 131072 + wave * 512 + lane * 8;
  const short* gb1 = gb0 + 2048;

  auto stage = [&](int kk, int buf) {
    const size_t koff = (size_t)kk * 4096;
    short* dA = &ldsA[buf][0];
    short* dB = &ldsB[buf][0];
    gld_lds16(ga0 + koff, dA + wave * 512);
    gld_lds16(ga1 + koff, dA + (wave + 4) * 512);
    gld_lds16(gb0 + koff, dB + wave * 512);
    gld_lds16(gb1 + koff, dB + (wave + 4) * 512);
  };
  auto compute = [&](int buf) {
    const short* sA = &ldsA[buf][0];
    const short* sB = &ldsB[buf][0];
    short8 af[4], bfr[4];
#pragma unroll
    for (int t = 0; t < 4; t++)
      af[t] = *(const short8*)&sA[((wr * 4 + t) * 64 + lane) * 8];
#pragma unroll
    for (int t = 0; t < 4; t++)
      bfr[t] = *(const short8*)&sB[((wc * 4 + t) * 64 + lane) * 8];
#pragma unroll
    for (int i = 0; i < 4; i++)
#pragma unroll
      for (int j = 0; j < 4; j++)
        acc[i][j] =
            __builtin_amdgcn_mfma_f32_16x16x32_bf16(af[i], bfr[j], acc[i][j], 0, 0, 0);
  };

  stage(0, 0);
  stage(1, 1);
  int cur = 0, nxt = 2;
  for (int i = 0; i < 30; ++i) {
    WAITVM(4);
    sbar();
    stage(i + 2, nxt);
    compute(cur);
    cur = (cur == 2) ? 0 : cur + 1;
    nxt = (nxt == 2) ? 0 : nxt + 1;
  }
  WAITVM(4);
  sbar();
  compute(cur);
  cur = (cur == 2) ? 0 : cur + 1;
  WAITVM(0);
  sbar();
  compute(cur);

#pragma unroll
  for (int i = 0; i < 4; i++)
#pragma unroll
    for (int j = 0; j < 4; j++)
#pragma unroll
      for (int r = 0; r < 4; r++) {
        const int gr = rt * 128 + wr * 64 + i * 16 + lg * 4 + r;
        const int gc = ct * 128 + wc * 64 + j * 16 + l15;
        float v = acc[i][j][r];
        if (isKV) {
          v += bias[gc];
          const int b = gr >> 11, m = gr & 2047;
          const int kv = gc >> 10, hh = (gc >> 6) & 15, d = gc & 63;
          if (kv == 0)
            kws[((((size_t)b * 16 + hh) * 2048 + m) << 6) + d] = f2bf(v);
          else {
            // permuted V^T column so attn's in-register P-frag order matches
            const int mp = (m & ~31) | (((m >> 2) & 3) << 3) |
                           (((m >> 4) & 1) << 2) | (m & 3);
            vtws[(((size_t)b * 16 + hh) * 64 + d) * 2048 + mp] = f2bf(v);
          }
        } else {
          const int b = gr >> 10, n = gr & 1023, hh = gc >> 6, d = gc & 63;
          qws[((((size_t)b * 16 + hh) * 1024 + n) << 6) + d] = f2bf(v * SCL2E);
        }
      }
}

// ---------------------------------------------------------------------------
// attn_split (R17 structure + T5 setprio): swapped QK^T in-register P;
// NBUF=2 K/V full-phase counted-vmcnt cover; all 8 mask uint4 preloaded;
// fully unrolled. 512 blocks x 512 threads, split-K x2. LDS 64KB.
// ---------------------------------------------------------------------------
__global__ __launch_bounds__(512, 4)
void attn_split(const short* __restrict__ Qg, const short* __restrict__ Kg,
                const short* __restrict__ Vtg,
                const unsigned int* __restrict__ pm,
                float* __restrict__ opart, float* __restrict__ lpart) {
  __shared__ __align__(16) short ldsK[2][8192];
  __shared__ __align__(16) short ldsV[2][8192];
  const int tid = threadIdx.x;
  const int w = tid >> 6, lane = tid & 63;
  const int l15 = lane & 15, lg = lane >> 4;
  const int bx = blockIdx.x;
  const int bhid = bx & 31, qt = (bx >> 5) & 7, half = bx >> 8;
  const int b = bhid >> 4, h = bhid & 15;
  const int n0 = qt * 128, m_base = half * 1024;
  const size_t bh = (size_t)b * 16 + h;
  const short* Qb = Qg + (bh * 1024 + n0) * 64;
  const short* Kb = Kg + (bh << 17);
  const short* Vb = Vtg + (bh << 17);
  const unsigned int* pmw =
      pm + ((size_t)(b * 1024 + n0 + w * 16 + l15) << 6) + (m_base >> 5);

  uint4 mku[8];
#pragma unroll
  for (int c = 0; c < 8; c++) mku[c] = *(const uint4*)(pmw + c * 4);

  auto stageKV = [&](int c, int buf) {
    const int m0 = m_base + c * 128;
    short* dK = &ldsK[buf][0];
    short* dV = &ldsV[buf][0];
#pragma unroll
    for (int ii = 0; ii < 2; ii++) {
      const int f = w * 2 + ii;
      const int t = f >> 1, ks = f & 1;
      gld_lds16(Kb + (size_t)(m0 + t * 16 + l15) * 64 + ks * 32 + lg * 8,
                dK + f * 512);
      const int vt = f >> 2, vk = f & 3;
      gld_lds16(Vb + (size_t)(vt * 16 + l15) * 2048 + (m0 + vk * 32 + lg * 8),
                dV + f * 512);
    }
  };

#pragma unroll
  for (int ii = 0; ii < 2; ii++)
    gld_lds16(Qb + (size_t)(w * 16 + l15) * 64 + ii * 32 + lg * 8,
              &ldsV[1][(w * 2 + ii) * 512]);
  stageKV(0, 0);
  pipesync();
  short8 qf[2];
#pragma unroll
  for (int ks = 0; ks < 2; ks++)
    qf[ks] = *(const short8*)&ldsV[1][((w * 2 + ks) * 64 + lane) * 8];
  asm volatile("s_waitcnt lgkmcnt(0)" ::: "memory");
  sbar();

  short8 onesf;
#pragma unroll
  for (int i = 0; i < 8; i++) onesf[i] = (short)0x3F80;  // bf16 1.0

  f32x4 o[4], lacc;
#pragma unroll
  for (int ct = 0; ct < 4; ct++) o[ct] = (f32x4){0.f, 0.f, 0.f, 0.f};
  lacc = (f32x4){0.f, 0.f, 0.f, 0.f};
  const int sb = lg * 4;

  auto computeC = [&](uint4 mk, int buf) {
    const short* sK = &ldsK[buf][0];
    const short* sV = &ldsV[buf][0];
    int4v pw4[4];
#pragma unroll
    for (int h2 = 0; h2 < 2; h2++) {
      f32x4 s[4];
#pragma unroll
      for (int t2 = 0; t2 < 4; t2++) s[t2] = (f32x4){0.f, 0.f, 0.f, 0.f};
      __builtin_amdgcn_s_setprio(1);
#pragma unroll
      for (int t2 = 0; t2 < 4; t2++) {
        const int t = h2 * 4 + t2;
#pragma unroll
        for (int ks = 0; ks < 2; ks++) {
          const short8 kf = *(const short8*)&sK[((t * 2 + ks) * 64 + lane) * 8];
          s[t2] = __builtin_amdgcn_mfma_f32_16x16x32_bf16(kf, qf[ks], s[t2], 0, 0, 0);
        }
      }
      __builtin_amdgcn_s_setprio(0);
#pragma unroll
      for (int t2 = 0; t2 < 4; t2++) {
        const int t = h2 * 4 + t2;
        const unsigned int mw = ((t >> 1) == 0) ? mk.x
                              : ((t >> 1) == 1) ? mk.y
                              : ((t >> 1) == 2) ? mk.z : mk.w;
        float p[4];
#pragma unroll
        for (int r = 0; r < 4; r++) {
          const bool att = (mw >> (((t & 1) << 4) + sb + r)) & 1;
          p[r] = exp2f(att ? s[t2][r] : -1e30f);
        }
        pw4[t >> 1][(t & 1) * 2] = cvt_pk_bf16(p[0], p[1]);
        pw4[t >> 1][(t & 1) * 2 + 1] = cvt_pk_bf16(p[2], p[3]);
      }
    }
    __builtin_amdgcn_s_setprio(1);
#pragma unroll
    for (int ks2 = 0; ks2 < 4; ks2++) {
      const short8 pf = __builtin_bit_cast(short8, pw4[ks2]);
#pragma unroll
      for (int ct = 0; ct < 4; ct++) {
        const short8 vf = *(const short8*)&sV[((ct * 4 + ks2) * 64 + lane) * 8];
        o[ct] = __builtin_amdgcn_mfma_f32_16x16x32_bf16(pf, vf, o[ct], 0, 0, 0);
      }
      lacc = __builtin_amdgcn_mfma_f32_16x16x32_bf16(pf, onesf, lacc, 0, 0, 0);
    }
    __builtin_amdgcn_s_setprio(0);
  };

#pragma unroll
  for (int c = 0; c < 8; c++) {
    if (c + 1 < 8) {
      stageKV(c + 1, (c + 1) & 1);
      WAITVM(4);
    } else {
      WAITVM(0);
    }
    sbar();
    computeC(mku[c], c & 1);
    sbar();
  }

#pragma unroll
  for (int ct = 0; ct < 4; ct++)
#pragma unroll
    for (int r = 0; r < 4; r++) {
      const int n = n0 + w * 16 + lg * 4 + r;
      opart[((size_t)half << 21) + (((size_t)b * 1024 + n) << 10) + h * 64 +
            ct * 16 + l15] = o[ct][r];
    }
  if (l15 == 0) {
#pragma unroll
    for (int r = 0; r < 4; r++) {
      const int n = n0 + w * 16 + lg * 4 + r;
      lpart[((size_t)half << 15) + bh * 1024 + n] = lacc[r];
    }
  }
}

// ---------------------------------------------------------------------------
// combine (R21, output-linear): AO = (o0+o1)/(l0+l1), bf16, 64-tiled.
// ---------------------------------------------------------------------------
__global__ __launch_bounds__(256) void combine(
    const float* __restrict__ opart, const float* __restrict__ lpart,
    short* __restrict__ aoT) {
  const int gid = blockIdx.x * 256 + threadIdx.x;  // [0, 524288)
  const int T = gid * 4;
  const int j = T & 4, r15 = (T >> 3) & 15, q = (T >> 7) & 3;
  const int f = (T >> 9) & 3, kc = (T >> 11) & 31, rt = T >> 16;
  const int row = rt * 64 + f * 16 + r15;
  const int col = kc * 32 + q * 8 + j;
  const int b = row >> 10, n = row & 1023, h = col >> 6;
  const size_t src = (((size_t)row) << 10) + col;
  const float4 o1 = *(const float4*)(opart + src);
  const float4 o2 = *(const float4*)(opart + (1u << 21) + src);
  const float l1 = lpart[(size_t)(b * 16 + h) * 1024 + n];
  const float l2 = lpart[(1u << 15) + (size_t)(b * 16 + h) * 1024 + n];
  const float inv = 1.f / fmaxf(l1 + l2, 1e-30f);
  short4v o;
  o[0] = f2bf((o1.x + o2.x) * inv); o[1] = f2bf((o1.y + o2.y) * inv);
  o[2] = f2bf((o1.z + o2.z) * inv); o[3] = f2bf((o1.w + o2.w) * inv);
  *(short4v*)(aoT + T) = o;
}

// ---------------------------------------------------------------------------
// o_gemm (R17, unchanged): 64x64 tiles, BK=64 (16 phases x 8 MFMA),
// 512 blocks, NBUF=3 (48KB LDS, 3 blocks/CU), counted vmcnt(4), XCD swizzle.
// ---------------------------------------------------------------------------
__global__ __launch_bounds__(256, 3)
void o_gemm(const short* __restrict__ aoT, const short* __restrict__ wobT,
            float* __restrict__ Of) {
  __shared__ __align__(16) short ldsA[3][4096];
  __shared__ __align__(16) short ldsB[3][4096];
  const int tid = threadIdx.x;
  const int w = tid >> 6, lane = tid & 63;
  const int l15 = lane & 15, lg = lane >> 4;
  const int bx0 = blockIdx.x;
  const int bx = (bx0 & 7) * 64 + (bx0 >> 3);
  const int rt = bx >> 4, ct = bx & 15;

  f32x4 acc[4];
#pragma unroll
  for (int j = 0; j < 4; j++) acc[j] = (f32x4){0.f, 0.f, 0.f, 0.f};

  const short* ga = aoT + (size_t)rt * 65536 + w * 512 + lane * 8;
  const short* gb = wobT + (size_t)ct * 65536 + w * 512 + lane * 8;

  auto stage = [&](int t, int buf) {
    const size_t koff = (size_t)t * 4096;
    gld_lds16(ga + koff, &ldsA[buf][0] + w * 512);
    gld_lds16(ga + koff + 2048, &ldsA[buf][0] + 2048 + w * 512);
    gld_lds16(gb + koff, &ldsB[buf][0] + w * 512);
    gld_lds16(gb + koff + 2048, &ldsB[buf][0] + 2048 + w * 512);
  };
  auto compute = [&](int buf) {
    const short* sA = &ldsA[buf][0];
    const short* sB = &ldsB[buf][0];
    const short8 af0 = *(const short8*)&sA[(w * 64 + lane) * 8];
    const short8 af1 = *(const short8*)&sA[2048 + (w * 64 + lane) * 8];
#pragma unroll
    for (int j = 0; j < 4; j++) {
      const short8 bf0 = *(const short8*)&sB[(j * 64 + lane) * 8];
      const short8 bf1 = *(const short8*)&sB[2048 + (j * 64 + lane) * 8];
      acc[j] = __builtin_amdgcn_mfma_f32_16x16x32_bf16(af0, bf0, acc[j], 0, 0, 0);
      acc[j] = __builtin_amdgcn_mfma_f32_16x16x32_bf16(af1, bf1, acc[j], 0, 0, 0);
    }
  };

  stage(0, 0);
  stage(1, 1);
#pragma unroll
  for (int i = 0; i < 14; ++i) {
    WAITVM(4);
    sbar();
    stage(i + 2, (i + 2) % 3);
    compute(i % 3);
  }
  WAITVM(4);
  sbar();
  compute(14 % 3);
  WAITVM(0);
  sbar();
  compute(15 % 3);

#pragma unroll
  for (int j = 0; j < 4; j++)
#pragma unroll
    for (int r = 0; r < 4; r++) {
      const int gr = rt * 64 + w * 16 + lg * 4 + r;
      const int gc = ct * 64 + j * 16 + l15;
      Of[(size_t)gr * 1024 + gc] = acc[j][r];
    }
}

extern "C" void kernel_launch(void* const* d_in, const int* in_sizes, int n_in,
                              void* d_out, int out_size, void* d_ws, size_t ws_size,
                              hipStream_t stream) {
  const float* x   = (const float*)d_in[0];   // fp32 (2,1024,1024)
  const float* ctx = (const float*)d_in[1];   // fp32 (2,2048,1024)
  const unsigned char* mask = (const unsigned char*)d_in[2];  // (2,1024,2048)
  const float* Wq  = (const float*)d_in[3];
  const float* Wkv = (const float*)d_in[4];
  const float* bkv = (const float*)d_in[5];
  const float* Wo  = (const float*)d_in[6];
  float* out = (float*)d_out;                 // FP32 (2,1024,1024)

  char* wsb = (char*)d_ws;
  short* qws  = (short*)(wsb);                        // bf16 Q*scl  4MB @0
  short* kws  = (short*)(wsb + (4u << 20));           // bf16 K      8MB @4M
  short* vtws = (short*)(wsb + (12u << 20));          // bf16 V^T    8MB @12M
  short* wqb  = (short*)(wsb + (20u << 20));          // bf16 Wq(T)  2MB @20M
  short* wkvb = (short*)(wsb + (22u << 20));          // bf16 Wkv(T) 4MB @22M
  short* wob  = (short*)(wsb + (26u << 20));          // bf16 Wo(T)  2MB @26M
  unsigned long long* pmws = (unsigned long long*)(wsb + (28u << 20));  // .5MB
  float* opart = (float*)(wsb + (29u << 20));         // fp32 2x8MB  16MB @29M
  float* lpart = (float*)(wsb + (45u << 20));         // fp32 .25MB  @45M
  short* xb   = (short*)(wsb + (29u << 20));          // bf16 x(T)   4MB @29M
  short* ctxb = (short*)(wsb + (33u << 20));          // bf16 ctx(T) 8MB @33M
  short* ao = (short*)(wsb + (20u << 20));  // bf16 AO(T) 4MB (reuses wqb/wkvb)

  prep<<<2048, 256, 0, stream>>>(mask, pmws, Wq, Wkv, Wo, x, ctx,
                                 wqb, wkvb, wob, xb, ctxb);
  qkv_gemm<<<640, 256, 0, stream>>>(xb, ctxb, wqb, wkvb, bkv, qws, kws, vtws);
  attn_split<<<512, 512, 0, stream>>>(qws, kws, vtws, (const unsigned int*)pmws,
                                      opart, lpart);
  combine<<<2048, 256, 0, stream>>>(opart, lpart, ao);
  o_gemm<<<512, 256, 0, stream>>>(ao, wob, out);
}